// Round 3
// baseline (560.853 us; speedup 1.0000x reference)
//
#include <hip/hip_runtime.h>
#include <math.h>

#define N_NODES 50000
#define N_EDGES 800000
#define N_TOT   850000   // edges + self loops
#define NSB     ((N_NODES + 255) / 256)   // scan blocks = 196

typedef __attribute__((ext_vector_type(8))) short short8;   // 8 bf16 (4 VGPRs)
typedef __attribute__((ext_vector_type(4))) float floatx4;  // MFMA acc

// ---------------------------- bf16 pack/unpack ------------------------------
__device__ __forceinline__ unsigned int pack_bf16x2(float a, float b) {
    unsigned ua = __float_as_uint(a);
    unsigned ub = __float_as_uint(b);
    ua += 0x7fff + ((ua >> 16) & 1);   // round-to-nearest-even
    ub += 0x7fff + ((ub >> 16) & 1);
    return (ua >> 16) | (ub & 0xffff0000u);
}
__device__ __forceinline__ unsigned short pack_bf16(float a) {
    unsigned ua = __float_as_uint(a);
    ua += 0x7fff + ((ua >> 16) & 1);
    return (unsigned short)(ua >> 16);
}
__device__ __forceinline__ float bf16_lo(unsigned u) { return __uint_as_float(u << 16); }
__device__ __forceinline__ float bf16_hi(unsigned u) { return __uint_as_float(u & 0xffff0000u); }

// ----------------------------- utility kernels -----------------------------
__global__ void zero_int_kernel(int* p, int n) {
    int i = blockIdx.x * blockDim.x + threadIdx.x;
    if (i < n) p[i] = 0;
}

// ----------------------------- CSR build -----------------------------------
__global__ void deg_hist_kernel(const int* __restrict__ ei, int* __restrict__ deg) {
    int e = blockIdx.x * blockDim.x + threadIdx.x;
    if (e >= N_TOT) return;
    int dst = (e < N_EDGES) ? ei[N_EDGES + e] : (e - N_EDGES);
    atomicAdd(&deg[dst], 1);
}

__global__ void block_scan_kernel(const int* __restrict__ deg, int* __restrict__ part,
                                  int* __restrict__ bsum) {
    __shared__ int tmp[256];
    int t = threadIdx.x;
    int i = blockIdx.x * 256 + t;
    int v = (i < N_NODES) ? deg[i] : 0;
    tmp[t] = v;
    __syncthreads();
    for (int d = 1; d < 256; d <<= 1) {
        int u = (t >= d) ? tmp[t - d] : 0;
        __syncthreads();
        tmp[t] += u;
        __syncthreads();
    }
    if (i < N_NODES) part[i] = tmp[t] - v;   // exclusive
    if (t == 255) bsum[blockIdx.x] = tmp[255];
}

__global__ void scan_bsum_kernel(int* __restrict__ bsum) {
    __shared__ int tmp[256];
    int t = threadIdx.x;
    int v = (t < NSB) ? bsum[t] : 0;
    tmp[t] = v;
    __syncthreads();
    for (int d = 1; d < 256; d <<= 1) {
        int u = (t >= d) ? tmp[t - d] : 0;
        __syncthreads();
        tmp[t] += u;
        __syncthreads();
    }
    if (t < NSB) bsum[t] = tmp[t] - v;       // exclusive block offsets
}

__global__ void finalize_off_kernel(const int* __restrict__ part, const int* __restrict__ bsum,
                                    int* __restrict__ off, int* __restrict__ cursor) {
    int i = blockIdx.x * 256 + threadIdx.x;
    if (i < N_NODES) {
        int o = part[i] + bsum[blockIdx.x];
        off[i] = o;
        cursor[i] = o;
    }
    if (i == 0) off[N_NODES] = N_TOT;
}

__global__ void fill_csr_kernel(const int* __restrict__ ei, int* __restrict__ cursor,
                                int* __restrict__ csr_src) {
    int e = blockIdx.x * blockDim.x + threadIdx.x;
    if (e >= N_TOT) return;
    int src, dst;
    if (e < N_EDGES) { src = ei[e]; dst = ei[N_EDGES + e]; }
    else             { src = dst = e - N_EDGES; }
    int pos = atomicAdd(&cursor[dst], 1);
    csr_src[pos] = src;
}

// --------------- weight convert: W [K][N] fp32 -> Wt [N][K] bf16 ------------
__global__ void wconv_kernel(const float* __restrict__ W1, const float* __restrict__ W2,
                             const float* __restrict__ W3, const float* __restrict__ W4,
                             unsigned short* __restrict__ T1, unsigned short* __restrict__ T2,
                             unsigned short* __restrict__ T3, unsigned short* __restrict__ T4) {
    int i = blockIdx.x * 256 + threadIdx.x;
    const float* W; unsigned short* T; int K, N, idx;
    if      (i < 32768) { W = W1; T = T1; K = 128; N = 256; idx = i; }
    else if (i < 40960) { W = W2; T = T2; K = 256; N = 32;  idx = i - 32768; }
    else if (i < 49152) { W = W3; T = T3; K = 32;  N = 256; idx = i - 40960; }
    else if (i < 81920) { W = W4; T = T4; K = 256; N = 128; idx = i - 49152; }
    else return;
    int n = idx / K, k = idx % K;
    T[idx] = pack_bf16(W[(size_t)k * N + n]);
}

// ------------------ fused MFMA GEMM + attention logits ----------------------
template<int Cin, int Cout, int H, int C, int NPB, int NW_N, bool IN_BF16>
__global__ void gemm_mfma_kernel(const void* __restrict__ xin,
                                 const unsigned short* __restrict__ Wt,
                                 const float* __restrict__ a_src, const float* __restrict__ a_dst,
                                 unsigned short* __restrict__ hb,
                                 float* __restrict__ al_s, float* __restrict__ al_d) {
    constexpr int NW_M = 4 / NW_N;
    constexpr int MT_W = (NPB / 16) / NW_M;   // m-tiles per wave
    constexpr int NT_W = (Cout / 16) / NW_N;  // n-tiles per wave
    constexpr int AS   = Cin + 8;             // A row stride (bf16 elems)
    constexpr int SP   = Cout + 4;            // hs row stride (floats)
    __shared__ unsigned short xs[NPB * AS];
    __shared__ float hs[NPB * SP];
    int tid = threadIdx.x;
    int n0  = blockIdx.x * NPB;

    // ---- stage A tile as bf16 ----
    if (IN_BF16) {
        for (int i = tid; i < NPB * Cin / 8; i += 256) {
            int n = i / (Cin / 8), k8 = i % (Cin / 8);
            uint4 q = make_uint4(0u, 0u, 0u, 0u);
            if (n0 + n < N_NODES)
                q = ((const uint4*)((const unsigned short*)xin + (size_t)(n0 + n) * Cin))[k8];
            *(uint4*)(xs + n * AS + k8 * 8) = q;
        }
    } else {
        for (int i = tid; i < NPB * Cin / 4; i += 256) {
            int n = i / (Cin / 4), k4 = i % (Cin / 4);
            float4 v = make_float4(0.f, 0.f, 0.f, 0.f);
            if (n0 + n < N_NODES)
                v = ((const float4*)((const float*)xin + (size_t)(n0 + n) * Cin))[k4];
            uint2 p;
            p.x = pack_bf16x2(v.x, v.y);
            p.y = pack_bf16x2(v.z, v.w);
            *(uint2*)(xs + n * AS + k4 * 4) = p;
        }
    }
    __syncthreads();

    int w = tid >> 6, lane = tid & 63;
    int q = lane >> 4, l16 = lane & 15;
    int wm = w / NW_N, wn = w % NW_N;
    int mbase = wm * MT_W * 16;
    int nbase = wn * NT_W * 16;

    floatx4 acc[MT_W][NT_W];
#pragma unroll
    for (int mt = 0; mt < MT_W; mt++)
#pragma unroll
        for (int nt = 0; nt < NT_W; nt++) acc[mt][nt] = (floatx4){0.f, 0.f, 0.f, 0.f};

#pragma unroll
    for (int k0 = 0; k0 < Cin; k0 += 32) {
        short8 a[MT_W], b[NT_W];
#pragma unroll
        for (int mt = 0; mt < MT_W; mt++)
            a[mt] = *(const short8*)(xs + (mbase + mt * 16 + l16) * AS + k0 + q * 8);
#pragma unroll
        for (int nt = 0; nt < NT_W; nt++)
            b[nt] = *(const short8*)(Wt + (size_t)(nbase + nt * 16 + l16) * Cin + k0 + q * 8);
#pragma unroll
        for (int mt = 0; mt < MT_W; mt++)
#pragma unroll
            for (int nt = 0; nt < NT_W; nt++)
                acc[mt][nt] = __builtin_amdgcn_mfma_f32_16x16x32_bf16(a[mt], b[nt], acc[mt][nt], 0, 0, 0);
    }

    // ---- C tiles -> LDS (row = q*4 + reg, col = l16; verified layout) ----
#pragma unroll
    for (int mt = 0; mt < MT_W; mt++)
#pragma unroll
        for (int nt = 0; nt < NT_W; nt++)
#pragma unroll
            for (int r = 0; r < 4; r++) {
                int nl = mbase + mt * 16 + q * 4 + r;
                int ch = nbase + nt * 16 + l16;
                hs[nl * SP + ch] = acc[mt][nt][r];
            }
    __syncthreads();

    // ---- epilogue: logits + bf16 h write ----
    constexpr int TPN = Cout / 32;            // threads per node (32 ch each)
    constexpr int TPH = (C > 32) ? (C / 32) : 1;  // threads sharing one head
    if (tid < NPB * TPN) {
        int node = tid / TPN, sub = tid % TPN;
        int gn = n0 + node;
        int head = (sub * 32) / C;
        int coff = (sub * 32) % C;
        const float* hrow = hs + node * SP + sub * 32;
        const float* ap = a_src + head * C + coff;
        const float* dp = a_dst + head * C + coff;
        float ps = 0.f, pd = 0.f;
#pragma unroll
        for (int c4 = 0; c4 < 8; c4++) {
            float4 hv = *(const float4*)(hrow + c4 * 4);
            float4 av = *(const float4*)(ap + c4 * 4);
            float4 dv = *(const float4*)(dp + c4 * 4);
            ps += hv.x * av.x + hv.y * av.y + hv.z * av.z + hv.w * av.w;
            pd += hv.x * dv.x + hv.y * dv.y + hv.z * dv.z + hv.w * dv.w;
        }
        // pack 32 bf16 = 16 u32
        uint4 o0, o1;
        {
            float4 h0 = *(const float4*)(hrow + 0);
            float4 h1 = *(const float4*)(hrow + 4);
            float4 h2 = *(const float4*)(hrow + 8);
            float4 h3 = *(const float4*)(hrow + 12);
            o0.x = pack_bf16x2(h0.x, h0.y); o0.y = pack_bf16x2(h0.z, h0.w);
            o0.z = pack_bf16x2(h1.x, h1.y); o0.w = pack_bf16x2(h1.z, h1.w);
            o1.x = pack_bf16x2(h2.x, h2.y); o1.y = pack_bf16x2(h2.z, h2.w);
            o1.z = pack_bf16x2(h3.x, h3.y); o1.w = pack_bf16x2(h3.z, h3.w);
        }
        uint4 o2, o3;
        {
            float4 h0 = *(const float4*)(hrow + 16);
            float4 h1 = *(const float4*)(hrow + 20);
            float4 h2 = *(const float4*)(hrow + 24);
            float4 h3 = *(const float4*)(hrow + 28);
            o2.x = pack_bf16x2(h0.x, h0.y); o2.y = pack_bf16x2(h0.z, h0.w);
            o2.z = pack_bf16x2(h1.x, h1.y); o2.w = pack_bf16x2(h1.z, h1.w);
            o3.x = pack_bf16x2(h2.x, h2.y); o3.y = pack_bf16x2(h2.z, h2.w);
            o3.z = pack_bf16x2(h3.x, h3.y); o3.w = pack_bf16x2(h3.z, h3.w);
        }
        if (gn < N_NODES) {
            uint2* dst = (uint2*)(hb + (size_t)gn * Cout + sub * 32);
            dst[0] = make_uint2(o0.x, o0.y); dst[1] = make_uint2(o0.z, o0.w);
            dst[2] = make_uint2(o1.x, o1.y); dst[3] = make_uint2(o1.z, o1.w);
            dst[4] = make_uint2(o2.x, o2.y); dst[5] = make_uint2(o2.z, o2.w);
            dst[6] = make_uint2(o3.x, o3.y); dst[7] = make_uint2(o3.z, o3.w);
        }
        if (TPH > 1) {
#pragma unroll
            for (int k = 1; k < TPH; k <<= 1) {
                ps += __shfl_xor(ps, k, 64);
                pd += __shfl_xor(pd, k, 64);
            }
            if ((sub % TPH) == 0 && gn < N_NODES) {
                al_s[gn * H + head] = ps;
                al_d[gn * H + head] = pd;
            }
        } else {
            if (gn < N_NODES) {
                al_s[gn * H + head] = ps;
                al_d[gn * H + head] = pd;
            }
        }
    }
}

// ------------------------- GAT softmax + aggregation ------------------------
// Single-pass unnormalized softmax (logits bounded, self loop => wsum>0).
// EB = min(SUB, 8): edge-batch width decoupled from lane-group width so the
// C=128 layer (SUB=32 > mean degree 17) gets clean full batches instead of
// one fully-masked 32-slot tail.
// Double-batch main loop: 2*EB edges per iteration -> 2*EB h-row gathers in
// flight per wave (MLP x2 vs round-1; counters showed latency-bound: HBM 46%,
// VALU 37%, nothing saturated).
template<int H, int C, bool RELU, bool OUT_BF16>
__launch_bounds__(256, 6)
__global__ void gat_agg_kernel(const unsigned short* __restrict__ hb,
                               const float* __restrict__ al_s,
                               const float* __restrict__ al_d, const int* __restrict__ off,
                               const int* __restrict__ csr_src, const float* __restrict__ bias,
                               void* __restrict__ out) {
    constexpr int HC  = H * C;
    constexpr int G   = HC / 4;    // lanes per node (64 / 32 / 8)
    constexpr int SUB = G / H;     // lanes per head
    constexpr int EB  = (SUB > 8) ? 8 : SUB;   // edges per batch
    constexpr int NPW = 64 / G;    // nodes per wave
    constexpr int NPB = 4 * NPW;   // nodes per 256-thread block

    int tid  = threadIdx.x;
    int wid  = tid >> 6;
    int lane = tid & 63;
    int gi   = lane / G;           // node slot within wave
    int g    = lane % G;           // lane within node group
    int node = blockIdx.x * NPB + wid * NPW + gi;
    if (node >= N_NODES) return;

    int head = g / SUB;            // this lane's head
    int es   = g % EB;             // edge slot within batch
    int nb   = lane & ~(G - 1);    // group base lane
    int r0 = off[node], r1 = off[node + 1];
    float ald = al_d[node * H + head];

    const uint2* hb2 = (const uint2*)hb;
    float4 acc = make_float4(0.f, 0.f, 0.f, 0.f);
    float wsum = 0.f;
    int j0 = r0;

    // ---- double batches: 2*EB edges, 2*EB gathers in flight ----
    for (; j0 + 2 * EB <= r1; j0 += 2 * EB) {
        int sA = csr_src[j0 + es];
        int sB = csr_src[j0 + EB + es];
        float eA = al_s[sA * H + head] + ald;
        float eB = al_s[sB * H + head] + ald;
        eA = fmaxf(eA, 0.2f * eA);
        eB = fmaxf(eB, 0.2f * eB);
        float wA = __expf(eA), wB = __expf(eB);
#pragma unroll
        for (int u = 0; u < EB; u++) {
            float wuA = __shfl(wA, nb + head * EB + u, 64);
            float wuB = __shfl(wB, nb + head * EB + u, 64);
            int suA, suB;
            if (NPW == 1) {
                suA = __builtin_amdgcn_readlane(sA, u);
                suB = __builtin_amdgcn_readlane(sB, u);
            } else {
                suA = __shfl(sA, nb + u, 64);
                suB = __shfl(sB, nb + u, 64);
            }
            uint2 qA = hb2[(size_t)suA * G + g];
            uint2 qB = hb2[(size_t)suB * G + g];
            wsum += wuA + wuB;
            acc.x += wuA * bf16_lo(qA.x) + wuB * bf16_lo(qB.x);
            acc.y += wuA * bf16_hi(qA.x) + wuB * bf16_hi(qB.x);
            acc.z += wuA * bf16_lo(qA.y) + wuB * bf16_lo(qB.y);
            acc.w += wuA * bf16_hi(qA.y) + wuB * bf16_hi(qB.y);
        }
    }
    // ---- single full batch ----
    if (j0 + EB <= r1) {
        int sA = csr_src[j0 + es];
        float eA = al_s[sA * H + head] + ald;
        eA = fmaxf(eA, 0.2f * eA);
        float wA = __expf(eA);
#pragma unroll
        for (int u = 0; u < EB; u++) {
            float wu = __shfl(wA, nb + head * EB + u, 64);
            int su = (NPW == 1) ? __builtin_amdgcn_readlane(sA, u)
                                : __shfl(sA, nb + u, 64);
            uint2 q = hb2[(size_t)su * G + g];
            wsum += wu;
            acc.x += wu * bf16_lo(q.x); acc.y += wu * bf16_hi(q.x);
            acc.z += wu * bf16_lo(q.y); acc.w += wu * bf16_hi(q.y);
        }
        j0 += EB;
    }
    // ---- masked tail (< EB edges) ----
    if (j0 < r1) {
        bool valid = (j0 + es) < r1;
        int sA = csr_src[valid ? (j0 + es) : (r1 - 1)];  // deg >= 1 (self loop)
        float eA = al_s[sA * H + head] + ald;
        eA = fmaxf(eA, 0.2f * eA);
        float wA = valid ? __expf(eA) : 0.f;
#pragma unroll
        for (int u = 0; u < EB; u++) {
            float wu = __shfl(wA, nb + head * EB + u, 64);
            if (wu != 0.f) {               // per-edge validity (group-uniform)
                int su = (NPW == 1) ? __builtin_amdgcn_readlane(sA, u)
                                    : __shfl(sA, nb + u, 64);
                uint2 q = hb2[(size_t)su * G + g];
                wsum += wu;
                acc.x += wu * bf16_lo(q.x); acc.y += wu * bf16_hi(q.x);
                acc.z += wu * bf16_lo(q.y); acc.w += wu * bf16_hi(q.y);
            }
        }
    }

    float inv = 1.f / wsum;                 // wsum > 0: self loop always valid
    float4 bv = ((const float4*)bias)[g];
    acc.x = acc.x * inv + bv.x;
    acc.y = acc.y * inv + bv.y;
    acc.z = acc.z * inv + bv.z;
    acc.w = acc.w * inv + bv.w;
    if (RELU) {
        acc.x = fmaxf(acc.x, 0.f); acc.y = fmaxf(acc.y, 0.f);
        acc.z = fmaxf(acc.z, 0.f); acc.w = fmaxf(acc.w, 0.f);
    }
    if (OUT_BF16) {
        uint2 p;
        p.x = pack_bf16x2(acc.x, acc.y);
        p.y = pack_bf16x2(acc.z, acc.w);
        ((uint2*)out)[(size_t)node * (HC / 4) + g] = p;
    } else {
        ((float4*)out)[(size_t)node * (HC / 4) + g] = acc;
    }
}

// ------------------------------- launcher -----------------------------------
extern "C" void kernel_launch(void* const* d_in, const int* in_sizes, int n_in,
                              void* d_out, int out_size, void* d_ws, size_t ws_size,
                              hipStream_t stream) {
    const float* x   = (const float*)d_in[0];
    const int*   ei  = (const int*)d_in[1];   // harness casts int64 -> int32
    const float* W1  = (const float*)d_in[2];
    const float* as1 = (const float*)d_in[3];
    const float* ad1 = (const float*)d_in[4];
    const float* b1  = (const float*)d_in[5];
    const float* W2  = (const float*)d_in[6];
    const float* as2 = (const float*)d_in[7];
    const float* ad2 = (const float*)d_in[8];
    const float* b2  = (const float*)d_in[9];
    const float* W3  = (const float*)d_in[10];
    const float* as3 = (const float*)d_in[11];
    const float* ad3 = (const float*)d_in[12];
    const float* b3  = (const float*)d_in[13];
    const float* W4  = (const float*)d_in[14];
    const float* as4 = (const float*)d_in[15];
    const float* ad4 = (const float*)d_in[16];
    const float* b4  = (const float*)d_in[17];

    char* ws = (char*)d_ws;
    size_t o = 0;
    auto alloc = [&](size_t bytes) -> void* {
        void* p = ws + o;
        o = (o + bytes + 255) & ~(size_t)255;
        return p;
    };
    unsigned short* feat_a  = (unsigned short*)alloc((size_t)N_NODES * 256 * 2); // 25.6 MB bf16
    unsigned short* feat_b  = (unsigned short*)alloc((size_t)N_NODES * 32 * 2);  // 3.2 MB bf16
    unsigned short* h_buf   = (unsigned short*)alloc((size_t)N_NODES * 256 * 2); // 25.6 MB bf16
    float*          al_s    = (float*)alloc((size_t)N_NODES * 8 * 4);
    float*          al_d    = (float*)alloc((size_t)N_NODES * 8 * 4);
    int*            deg     = (int*)alloc((size_t)(N_NODES + 1) * 4);
    int*            off     = (int*)alloc((size_t)(N_NODES + 1) * 4);
    int*            cursor  = (int*)alloc((size_t)N_NODES * 4);
    int*            part    = (int*)alloc((size_t)N_NODES * 4);
    int*            bsum    = (int*)alloc((size_t)256 * 4);
    int*            csr_src = (int*)alloc((size_t)N_TOT * 4);
    unsigned short* w1t     = (unsigned short*)alloc(32768 * 2);  // [256][128]
    unsigned short* w2t     = (unsigned short*)alloc(8192 * 2);   // [32][256]
    unsigned short* w3t     = (unsigned short*)alloc(8192 * 2);   // [256][32]
    unsigned short* w4t     = (unsigned short*)alloc(32768 * 2);  // [128][256]

    const int TPB = 256;
    int nb_nodes = (N_NODES + TPB - 1) / TPB;   // = NSB
    int nb_edges = (N_TOT + TPB - 1) / TPB;

    // ---- CSR build (by dst), parallel scan; weight convert ----
    zero_int_kernel<<<nb_nodes, TPB, 0, stream>>>(deg, N_NODES);
    wconv_kernel<<<320, TPB, 0, stream>>>(W1, W2, W3, W4, w1t, w2t, w3t, w4t);
    deg_hist_kernel<<<nb_edges, TPB, 0, stream>>>(ei, deg);
    block_scan_kernel<<<NSB, TPB, 0, stream>>>(deg, part, bsum);
    scan_bsum_kernel<<<1, TPB, 0, stream>>>(bsum);
    finalize_off_kernel<<<NSB, TPB, 0, stream>>>(part, bsum, off, cursor);
    fill_csr_kernel<<<nb_edges, TPB, 0, stream>>>(ei, cursor, csr_src);

    auto agg_blocks = [](int hc) { return (N_NODES * (hc / 4) + 255) / 256; };

    // ---- Layer 1: 128 -> (8 heads x 32), ReLU ----
    gemm_mfma_kernel<128, 256, 8, 32, 32, 4, false>
        <<<(N_NODES + 31) / 32, TPB, 0, stream>>>(x, w1t, as1, ad1, h_buf, al_s, al_d);
    gat_agg_kernel<8, 32, true, true><<<agg_blocks(256), TPB, 0, stream>>>(h_buf, al_s, al_d, off, csr_src, b1, feat_a);

    // ---- Layer 2: 256 -> 32, 1 head ----
    gemm_mfma_kernel<256, 32, 1, 32, 64, 2, true>
        <<<(N_NODES + 63) / 64, TPB, 0, stream>>>(feat_a, w2t, as2, ad2, h_buf, al_s, al_d);
    gat_agg_kernel<1, 32, false, true><<<agg_blocks(32), TPB, 0, stream>>>(h_buf, al_s, al_d, off, csr_src, b2, feat_b);

    // ---- Layer 3: 32 -> (8 heads x 32), ReLU ----
    gemm_mfma_kernel<32, 256, 8, 32, 32, 4, true>
        <<<(N_NODES + 31) / 32, TPB, 0, stream>>>(feat_b, w3t, as3, ad3, h_buf, al_s, al_d);
    gat_agg_kernel<8, 32, true, true><<<agg_blocks(256), TPB, 0, stream>>>(h_buf, al_s, al_d, off, csr_src, b3, feat_a);

    // ---- Layer 4: 256 -> 128, 1 head ----
    gemm_mfma_kernel<256, 128, 1, 128, 32, 4, true>
        <<<(N_NODES + 31) / 32, TPB, 0, stream>>>(feat_a, w4t, as4, ad4, h_buf, al_s, al_d);
    gat_agg_kernel<1, 128, false, false><<<agg_blocks(128), TPB, 0, stream>>>(h_buf, al_s, al_d, off, csr_src, b4, d_out);
}

// Round 4
// 483.562 us; speedup vs baseline: 1.1598x; 1.1598x over previous
//
#include <hip/hip_runtime.h>
#include <math.h>

#define N_NODES 50000
#define N_EDGES 800000
#define N_TOT   850000   // edges + self loops
#define NSB     ((N_NODES + 255) / 256)   // scan blocks = 196

typedef __attribute__((ext_vector_type(8))) short short8;   // 8 bf16 (4 VGPRs)
typedef __attribute__((ext_vector_type(4))) float floatx4;  // MFMA acc

// ---------------------------- bf16 pack/unpack ------------------------------
__device__ __forceinline__ unsigned int pack_bf16x2(float a, float b) {
    unsigned ua = __float_as_uint(a);
    unsigned ub = __float_as_uint(b);
    ua += 0x7fff + ((ua >> 16) & 1);   // round-to-nearest-even
    ub += 0x7fff + ((ub >> 16) & 1);
    return (ua >> 16) | (ub & 0xffff0000u);
}
__device__ __forceinline__ unsigned short pack_bf16(float a) {
    unsigned ua = __float_as_uint(a);
    ua += 0x7fff + ((ua >> 16) & 1);
    return (unsigned short)(ua >> 16);
}
__device__ __forceinline__ float bf16_lo(unsigned u) { return __uint_as_float(u << 16); }
__device__ __forceinline__ float bf16_hi(unsigned u) { return __uint_as_float(u & 0xffff0000u); }

// ----------------------------- utility kernels -----------------------------
__global__ void zero_int_kernel(int* p, int n) {
    int i = blockIdx.x * blockDim.x + threadIdx.x;
    if (i < n) p[i] = 0;
}

// ----------------------------- CSR build -----------------------------------
__global__ void deg_hist_kernel(const int* __restrict__ ei, int* __restrict__ deg) {
    int e = blockIdx.x * blockDim.x + threadIdx.x;
    if (e >= N_TOT) return;
    int dst = (e < N_EDGES) ? ei[N_EDGES + e] : (e - N_EDGES);
    atomicAdd(&deg[dst], 1);
}

__global__ void block_scan_kernel(const int* __restrict__ deg, int* __restrict__ part,
                                  int* __restrict__ bsum) {
    __shared__ int tmp[256];
    int t = threadIdx.x;
    int i = blockIdx.x * 256 + t;
    int v = (i < N_NODES) ? deg[i] : 0;
    tmp[t] = v;
    __syncthreads();
    for (int d = 1; d < 256; d <<= 1) {
        int u = (t >= d) ? tmp[t - d] : 0;
        __syncthreads();
        tmp[t] += u;
        __syncthreads();
    }
    if (i < N_NODES) part[i] = tmp[t] - v;   // exclusive
    if (t == 255) bsum[blockIdx.x] = tmp[255];
}

__global__ void scan_bsum_kernel(int* __restrict__ bsum) {
    __shared__ int tmp[256];
    int t = threadIdx.x;
    int v = (t < NSB) ? bsum[t] : 0;
    tmp[t] = v;
    __syncthreads();
    for (int d = 1; d < 256; d <<= 1) {
        int u = (t >= d) ? tmp[t - d] : 0;
        __syncthreads();
        tmp[t] += u;
        __syncthreads();
    }
    if (t < NSB) bsum[t] = tmp[t] - v;       // exclusive block offsets
}

__global__ void finalize_off_kernel(const int* __restrict__ part, const int* __restrict__ bsum,
                                    int* __restrict__ off, int* __restrict__ cursor) {
    int i = blockIdx.x * 256 + threadIdx.x;
    if (i < N_NODES) {
        int o = part[i] + bsum[blockIdx.x];
        off[i] = o;
        cursor[i] = o;
    }
    if (i == 0) off[N_NODES] = N_TOT;
}

__global__ void fill_csr_kernel(const int* __restrict__ ei, int* __restrict__ cursor,
                                int* __restrict__ csr_src) {
    int e = blockIdx.x * blockDim.x + threadIdx.x;
    if (e >= N_TOT) return;
    int src, dst;
    if (e < N_EDGES) { src = ei[e]; dst = ei[N_EDGES + e]; }
    else             { src = dst = e - N_EDGES; }
    int pos = atomicAdd(&cursor[dst], 1);
    csr_src[pos] = src;
}

// --------------- weight convert: W [K][N] fp32 -> Wt [N][K] bf16 ------------
__global__ void wconv_kernel(const float* __restrict__ W1, const float* __restrict__ W2,
                             const float* __restrict__ W3, const float* __restrict__ W4,
                             unsigned short* __restrict__ T1, unsigned short* __restrict__ T2,
                             unsigned short* __restrict__ T3, unsigned short* __restrict__ T4) {
    int i = blockIdx.x * 256 + threadIdx.x;
    const float* W; unsigned short* T; int K, N, idx;
    if      (i < 32768) { W = W1; T = T1; K = 128; N = 256; idx = i; }
    else if (i < 40960) { W = W2; T = T2; K = 256; N = 32;  idx = i - 32768; }
    else if (i < 49152) { W = W3; T = T3; K = 32;  N = 256; idx = i - 40960; }
    else if (i < 81920) { W = W4; T = T4; K = 256; N = 128; idx = i - 49152; }
    else return;
    int n = idx / K, k = idx % K;
    T[idx] = pack_bf16(W[(size_t)k * N + n]);
}

// ------------------ fused MFMA GEMM + attention logits ----------------------
template<int Cin, int Cout, int H, int C, int NPB, int NW_N, bool IN_BF16>
__global__ void gemm_mfma_kernel(const void* __restrict__ xin,
                                 const unsigned short* __restrict__ Wt,
                                 const float* __restrict__ a_src, const float* __restrict__ a_dst,
                                 unsigned short* __restrict__ hb,
                                 float* __restrict__ al_s, float* __restrict__ al_d) {
    constexpr int NW_M = 4 / NW_N;
    constexpr int MT_W = (NPB / 16) / NW_M;   // m-tiles per wave
    constexpr int NT_W = (Cout / 16) / NW_N;  // n-tiles per wave
    constexpr int AS   = Cin + 8;             // A row stride (bf16 elems)
    constexpr int SP   = Cout + 4;            // hs row stride (floats)
    __shared__ unsigned short xs[NPB * AS];
    __shared__ float hs[NPB * SP];
    int tid = threadIdx.x;
    int n0  = blockIdx.x * NPB;

    // ---- stage A tile as bf16 ----
    if (IN_BF16) {
        for (int i = tid; i < NPB * Cin / 8; i += 256) {
            int n = i / (Cin / 8), k8 = i % (Cin / 8);
            uint4 q = make_uint4(0u, 0u, 0u, 0u);
            if (n0 + n < N_NODES)
                q = ((const uint4*)((const unsigned short*)xin + (size_t)(n0 + n) * Cin))[k8];
            *(uint4*)(xs + n * AS + k8 * 8) = q;
        }
    } else {
        for (int i = tid; i < NPB * Cin / 4; i += 256) {
            int n = i / (Cin / 4), k4 = i % (Cin / 4);
            float4 v = make_float4(0.f, 0.f, 0.f, 0.f);
            if (n0 + n < N_NODES)
                v = ((const float4*)((const float*)xin + (size_t)(n0 + n) * Cin))[k4];
            uint2 p;
            p.x = pack_bf16x2(v.x, v.y);
            p.y = pack_bf16x2(v.z, v.w);
            *(uint2*)(xs + n * AS + k4 * 4) = p;
        }
    }
    __syncthreads();

    int w = tid >> 6, lane = tid & 63;
    int q = lane >> 4, l16 = lane & 15;
    int wm = w / NW_N, wn = w % NW_N;
    int mbase = wm * MT_W * 16;
    int nbase = wn * NT_W * 16;

    floatx4 acc[MT_W][NT_W];
#pragma unroll
    for (int mt = 0; mt < MT_W; mt++)
#pragma unroll
        for (int nt = 0; nt < NT_W; nt++) acc[mt][nt] = (floatx4){0.f, 0.f, 0.f, 0.f};

#pragma unroll
    for (int k0 = 0; k0 < Cin; k0 += 32) {
        short8 a[MT_W], b[NT_W];
#pragma unroll
        for (int mt = 0; mt < MT_W; mt++)
            a[mt] = *(const short8*)(xs + (mbase + mt * 16 + l16) * AS + k0 + q * 8);
#pragma unroll
        for (int nt = 0; nt < NT_W; nt++)
            b[nt] = *(const short8*)(Wt + (size_t)(nbase + nt * 16 + l16) * Cin + k0 + q * 8);
#pragma unroll
        for (int mt = 0; mt < MT_W; mt++)
#pragma unroll
            for (int nt = 0; nt < NT_W; nt++)
                acc[mt][nt] = __builtin_amdgcn_mfma_f32_16x16x32_bf16(a[mt], b[nt], acc[mt][nt], 0, 0, 0);
    }

    // ---- C tiles -> LDS (row = q*4 + reg, col = l16; verified layout) ----
#pragma unroll
    for (int mt = 0; mt < MT_W; mt++)
#pragma unroll
        for (int nt = 0; nt < NT_W; nt++)
#pragma unroll
            for (int r = 0; r < 4; r++) {
                int nl = mbase + mt * 16 + q * 4 + r;
                int ch = nbase + nt * 16 + l16;
                hs[nl * SP + ch] = acc[mt][nt][r];
            }
    __syncthreads();

    // ---- epilogue: logits + bf16 h write ----
    constexpr int TPN = Cout / 32;            // threads per node (32 ch each)
    constexpr int TPH = (C > 32) ? (C / 32) : 1;  // threads sharing one head
    if (tid < NPB * TPN) {
        int node = tid / TPN, sub = tid % TPN;
        int gn = n0 + node;
        int head = (sub * 32) / C;
        int coff = (sub * 32) % C;
        const float* hrow = hs + node * SP + sub * 32;
        const float* ap = a_src + head * C + coff;
        const float* dp = a_dst + head * C + coff;
        float ps = 0.f, pd = 0.f;
#pragma unroll
        for (int c4 = 0; c4 < 8; c4++) {
            float4 hv = *(const float4*)(hrow + c4 * 4);
            float4 av = *(const float4*)(ap + c4 * 4);
            float4 dv = *(const float4*)(dp + c4 * 4);
            ps += hv.x * av.x + hv.y * av.y + hv.z * av.z + hv.w * av.w;
            pd += hv.x * dv.x + hv.y * dv.y + hv.z * dv.z + hv.w * dv.w;
        }
        // pack 32 bf16 = 16 u32
        uint4 o0, o1;
        {
            float4 h0 = *(const float4*)(hrow + 0);
            float4 h1 = *(const float4*)(hrow + 4);
            float4 h2 = *(const float4*)(hrow + 8);
            float4 h3 = *(const float4*)(hrow + 12);
            o0.x = pack_bf16x2(h0.x, h0.y); o0.y = pack_bf16x2(h0.z, h0.w);
            o0.z = pack_bf16x2(h1.x, h1.y); o0.w = pack_bf16x2(h1.z, h1.w);
            o1.x = pack_bf16x2(h2.x, h2.y); o1.y = pack_bf16x2(h2.z, h2.w);
            o1.z = pack_bf16x2(h3.x, h3.y); o1.w = pack_bf16x2(h3.z, h3.w);
        }
        uint4 o2, o3;
        {
            float4 h0 = *(const float4*)(hrow + 16);
            float4 h1 = *(const float4*)(hrow + 20);
            float4 h2 = *(const float4*)(hrow + 24);
            float4 h3 = *(const float4*)(hrow + 28);
            o2.x = pack_bf16x2(h0.x, h0.y); o2.y = pack_bf16x2(h0.z, h0.w);
            o2.z = pack_bf16x2(h1.x, h1.y); o2.w = pack_bf16x2(h1.z, h1.w);
            o3.x = pack_bf16x2(h2.x, h2.y); o3.y = pack_bf16x2(h2.z, h2.w);
            o3.z = pack_bf16x2(h3.x, h3.y); o3.w = pack_bf16x2(h3.z, h3.w);
        }
        if (gn < N_NODES) {
            uint2* dst = (uint2*)(hb + (size_t)gn * Cout + sub * 32);
            dst[0] = make_uint2(o0.x, o0.y); dst[1] = make_uint2(o0.z, o0.w);
            dst[2] = make_uint2(o1.x, o1.y); dst[3] = make_uint2(o1.z, o1.w);
            dst[4] = make_uint2(o2.x, o2.y); dst[5] = make_uint2(o2.z, o2.w);
            dst[6] = make_uint2(o3.x, o3.y); dst[7] = make_uint2(o3.z, o3.w);
        }
        if (TPH > 1) {
#pragma unroll
            for (int k = 1; k < TPH; k <<= 1) {
                ps += __shfl_xor(ps, k, 64);
                pd += __shfl_xor(pd, k, 64);
            }
            if ((sub % TPH) == 0 && gn < N_NODES) {
                al_s[gn * H + head] = ps;
                al_d[gn * H + head] = pd;
            }
        } else {
            if (gn < N_NODES) {
                al_s[gn * H + head] = ps;
                al_d[gn * H + head] = pd;
            }
        }
    }
}

// ------------------------- GAT softmax + aggregation ------------------------
// Single-pass unnormalized softmax (logits bounded, self loop => wsum>0).
// Round-1 single-batch structure + SCALAR-CHAIN PIPELINE: prefetch next
// batch's csr_src + al_s (2 live scalars, ~4 VGPR) while the current batch's
// inner unroll runs. Round-3 lesson: widening the h-row gather queue (16 in
// flight) spilled the in-flight loads to scratch (WRITE_SIZE 25->144 MB,
// VALUBusy 37->24) -- MLP must come from pipelining the cheap scalar chain,
// not from doubling the wide gather side.
// EB = min(SUB, 8): layer 4 (SUB=32 > mean degree 17) gets clean batches
// instead of one mostly-masked 32-slot pass.
template<int H, int C, bool RELU, bool OUT_BF16>
__launch_bounds__(256, 6)
__global__ void gat_agg_kernel(const unsigned short* __restrict__ hb,
                               const float* __restrict__ al_s,
                               const float* __restrict__ al_d, const int* __restrict__ off,
                               const int* __restrict__ csr_src, const float* __restrict__ bias,
                               void* __restrict__ out) {
    constexpr int HC  = H * C;
    constexpr int G   = HC / 4;    // lanes per node (64 / 32 / 8)
    constexpr int SUB = G / H;     // lanes per head
    constexpr int EB  = (SUB > 8) ? 8 : SUB;   // edges per batch
    constexpr int NPW = 64 / G;    // nodes per wave
    constexpr int NPB = 4 * NPW;   // nodes per 256-thread block

    int tid  = threadIdx.x;
    int wid  = tid >> 6;
    int lane = tid & 63;
    int gi   = lane / G;           // node slot within wave
    int g    = lane % G;           // lane within node group
    int node = blockIdx.x * NPB + wid * NPW + gi;
    if (node >= N_NODES) return;

    int head = g / SUB;            // this lane's head
    int es   = g % EB;             // edge slot within batch
    int nb   = lane & ~(G - 1);    // group base lane
    int r0 = off[node], r1 = off[node + 1];
    float ald = al_d[node * H + head];

    const uint2* hb2 = (const uint2*)hb;
    float4 acc = make_float4(0.f, 0.f, 0.f, 0.f);
    float wsum = 0.f;

    // ---- prologue: load batch-0 scalars (clamped; validity applied later) ---
    int j0 = r0;
    int idx0 = j0 + es;
    int sC = csr_src[(idx0 < r1) ? idx0 : (r1 - 1)];   // deg>=1 (self loop)
    float eC = al_s[sC * H + head] + ald;

    // ---- full batches: prefetch next scalars, then unmasked inner unroll ---
    for (; j0 + EB <= r1; j0 += EB) {
        int idxn = j0 + EB + es;
        int sN = csr_src[(idxn < r1) ? idxn : (r1 - 1)];   // prefetch next csr
        float eL = fmaxf(eC, 0.2f * eC);                   // leaky relu
        float wC = __expf(eL);                             // unnormalized weight
        float eN = al_s[sN * H + head] + ald;              // prefetch next logit
#pragma unroll
        for (int u = 0; u < EB; u++) {
            float wu = __shfl(wC, nb + head * EB + u, 64);
            int su = (NPW == 1) ? __builtin_amdgcn_readlane(sC, u)
                                : __shfl(sC, nb + u, 64);
            uint2 q = hb2[(size_t)su * G + g];
            wsum += wu;
            acc.x += wu * bf16_lo(q.x); acc.y += wu * bf16_hi(q.x);
            acc.z += wu * bf16_lo(q.y); acc.w += wu * bf16_hi(q.y);
        }
        sC = sN; eC = eN;
    }
    // ---- masked tail (< EB edges): scalars already loaded ----
    if (j0 < r1) {
        bool valid = (j0 + es) < r1;
        float eL = fmaxf(eC, 0.2f * eC);
        float wC = valid ? __expf(eL) : 0.f;
#pragma unroll
        for (int u = 0; u < EB; u++) {
            float wu = __shfl(wC, nb + head * EB + u, 64);
            if (wu != 0.f) {               // per-edge validity (group-uniform)
                int su = (NPW == 1) ? __builtin_amdgcn_readlane(sC, u)
                                    : __shfl(sC, nb + u, 64);
                uint2 q = hb2[(size_t)su * G + g];
                wsum += wu;
                acc.x += wu * bf16_lo(q.x); acc.y += wu * bf16_hi(q.x);
                acc.z += wu * bf16_lo(q.y); acc.w += wu * bf16_hi(q.y);
            }
        }
    }

    float inv = 1.f / wsum;                 // wsum > 0: self loop always valid
    float4 bv = ((const float4*)bias)[g];
    acc.x = acc.x * inv + bv.x;
    acc.y = acc.y * inv + bv.y;
    acc.z = acc.z * inv + bv.z;
    acc.w = acc.w * inv + bv.w;
    if (RELU) {
        acc.x = fmaxf(acc.x, 0.f); acc.y = fmaxf(acc.y, 0.f);
        acc.z = fmaxf(acc.z, 0.f); acc.w = fmaxf(acc.w, 0.f);
    }
    if (OUT_BF16) {
        uint2 p;
        p.x = pack_bf16x2(acc.x, acc.y);
        p.y = pack_bf16x2(acc.z, acc.w);
        ((uint2*)out)[(size_t)node * (HC / 4) + g] = p;
    } else {
        ((float4*)out)[(size_t)node * (HC / 4) + g] = acc;
    }
}

// ------------------------------- launcher -----------------------------------
extern "C" void kernel_launch(void* const* d_in, const int* in_sizes, int n_in,
                              void* d_out, int out_size, void* d_ws, size_t ws_size,
                              hipStream_t stream) {
    const float* x   = (const float*)d_in[0];
    const int*   ei  = (const int*)d_in[1];   // harness casts int64 -> int32
    const float* W1  = (const float*)d_in[2];
    const float* as1 = (const float*)d_in[3];
    const float* ad1 = (const float*)d_in[4];
    const float* b1  = (const float*)d_in[5];
    const float* W2  = (const float*)d_in[6];
    const float* as2 = (const float*)d_in[7];
    const float* ad2 = (const float*)d_in[8];
    const float* b2  = (const float*)d_in[9];
    const float* W3  = (const float*)d_in[10];
    const float* as3 = (const float*)d_in[11];
    const float* ad3 = (const float*)d_in[12];
    const float* b3  = (const float*)d_in[13];
    const float* W4  = (const float*)d_in[14];
    const float* as4 = (const float*)d_in[15];
    const float* ad4 = (const float*)d_in[16];
    const float* b4  = (const float*)d_in[17];

    char* ws = (char*)d_ws;
    size_t o = 0;
    auto alloc = [&](size_t bytes) -> void* {
        void* p = ws + o;
        o = (o + bytes + 255) & ~(size_t)255;
        return p;
    };
    unsigned short* feat_a  = (unsigned short*)alloc((size_t)N_NODES * 256 * 2); // 25.6 MB bf16
    unsigned short* feat_b  = (unsigned short*)alloc((size_t)N_NODES * 32 * 2);  // 3.2 MB bf16
    unsigned short* h_buf   = (unsigned short*)alloc((size_t)N_NODES * 256 * 2); // 25.6 MB bf16
    float*          al_s    = (float*)alloc((size_t)N_NODES * 8 * 4);
    float*          al_d    = (float*)alloc((size_t)N_NODES * 8 * 4);
    int*            deg     = (int*)alloc((size_t)(N_NODES + 1) * 4);
    int*            off     = (int*)alloc((size_t)(N_NODES + 1) * 4);
    int*            cursor  = (int*)alloc((size_t)N_NODES * 4);
    int*            part    = (int*)alloc((size_t)N_NODES * 4);
    int*            bsum    = (int*)alloc((size_t)256 * 4);
    int*            csr_src = (int*)alloc((size_t)N_TOT * 4);
    unsigned short* w1t     = (unsigned short*)alloc(32768 * 2);  // [256][128]
    unsigned short* w2t     = (unsigned short*)alloc(8192 * 2);   // [32][256]
    unsigned short* w3t     = (unsigned short*)alloc(8192 * 2);   // [256][32]
    unsigned short* w4t     = (unsigned short*)alloc(32768 * 2);  // [128][256]

    const int TPB = 256;
    int nb_nodes = (N_NODES + TPB - 1) / TPB;   // = NSB
    int nb_edges = (N_TOT + TPB - 1) / TPB;

    // ---- CSR build (by dst), parallel scan; weight convert ----
    zero_int_kernel<<<nb_nodes, TPB, 0, stream>>>(deg, N_NODES);
    wconv_kernel<<<320, TPB, 0, stream>>>(W1, W2, W3, W4, w1t, w2t, w3t, w4t);
    deg_hist_kernel<<<nb_edges, TPB, 0, stream>>>(ei, deg);
    block_scan_kernel<<<NSB, TPB, 0, stream>>>(deg, part, bsum);
    scan_bsum_kernel<<<1, TPB, 0, stream>>>(bsum);
    finalize_off_kernel<<<NSB, TPB, 0, stream>>>(part, bsum, off, cursor);
    fill_csr_kernel<<<nb_edges, TPB, 0, stream>>>(ei, cursor, csr_src);

    auto agg_blocks = [](int hc) { return (N_NODES * (hc / 4) + 255) / 256; };

    // ---- Layer 1: 128 -> (8 heads x 32), ReLU ----
    gemm_mfma_kernel<128, 256, 8, 32, 32, 4, false>
        <<<(N_NODES + 31) / 32, TPB, 0, stream>>>(x, w1t, as1, ad1, h_buf, al_s, al_d);
    gat_agg_kernel<8, 32, true, true><<<agg_blocks(256), TPB, 0, stream>>>(h_buf, al_s, al_d, off, csr_src, b1, feat_a);

    // ---- Layer 2: 256 -> 32, 1 head ----
    gemm_mfma_kernel<256, 32, 1, 32, 64, 2, true>
        <<<(N_NODES + 63) / 64, TPB, 0, stream>>>(feat_a, w2t, as2, ad2, h_buf, al_s, al_d);
    gat_agg_kernel<1, 32, false, true><<<agg_blocks(32), TPB, 0, stream>>>(h_buf, al_s, al_d, off, csr_src, b2, feat_b);

    // ---- Layer 3: 32 -> (8 heads x 32), ReLU ----
    gemm_mfma_kernel<32, 256, 8, 32, 32, 4, true>
        <<<(N_NODES + 31) / 32, TPB, 0, stream>>>(feat_b, w3t, as3, ad3, h_buf, al_s, al_d);
    gat_agg_kernel<8, 32, true, true><<<agg_blocks(256), TPB, 0, stream>>>(h_buf, al_s, al_d, off, csr_src, b3, feat_a);

    // ---- Layer 4: 256 -> 128, 1 head ----
    gemm_mfma_kernel<256, 128, 1, 128, 32, 4, true>
        <<<(N_NODES + 31) / 32, TPB, 0, stream>>>(feat_a, w4t, as4, ad4, h_buf, al_s, al_d);
    gat_agg_kernel<1, 128, false, false><<<agg_blocks(128), TPB, 0, stream>>>(h_buf, al_s, al_d, off, csr_src, b4, d_out);
}